// Round 1
// baseline (149.814 us; speedup 1.0000x reference)
//
#include <hip/hip_runtime.h>
#include <math.h>

// CTC batch cost (keras.backend.ctc_batch_cost, full lengths).
// B=512, T=512, C=96 (blank=95), L=64, S=2L+1=129.
//
// One 64-lane wave per batch item, wave-synchronous (no barriers).
// Linear-domain forward recurrence; exact power-of-2 rescale every 8 steps,
// computed at group end and APPLIED 4 steps later (off the critical chain).
//
// Round 6: double-depth global prefetch.
//  - R5 post-mortem: with 2 waves/CU (1/SIMD) there is zero TLP; the
//    single-chunk prefetch distance (~1.1k cyc of issue work) is shorter
//    than contended HBM latency (~2.3k cyc at 512 streaming waves), so
//    every chunk pays a vmcnt drain before SWRITE.
//  - Now: TWO named staging sets (G/H, 24 float4), chunk loop unrolled x2
//    so set alternation is static. Prefetch distance = 2 chunks; steady
//    state keeps <=24 loads in flight, compiler waits at vmcnt(12) and the
//    younger set stays outstanding across the wait.
//  - EPS folded into the staged values at SWRITE time (48 VALU/chunk vs 64,
//    and off the per-step critical chain).
//  - __launch_bounds__(64,1): VGPRs are free at this occupancy (~200 used).

constexpr int Bv = 512;
constexpr int Tv = 512;
constexpr int Cv = 96;
constexpr int Lv = 64;
constexpr int BLANK = Cv - 1;        // 95
constexpr float EPSf = 1e-7f;

constexpr int ROWS = 32;             // rows per chunk
constexpr int NCH  = Tv / ROWS;      // 16 chunks
constexpr int CF   = ROWS * Cv;      // 3072 floats per chunk in global
constexpr int RS   = 100;            // padded LDS row stride (floats); 400 B
constexpr int LBUF = ROWS * RS;      // 3200 floats per LDS buffer

__device__ __forceinline__ float dpp_shr1(float x) {   // lane i <- i-1; lane0 <- 0
    return __int_as_float(
        __builtin_amdgcn_update_dpp(0, __float_as_int(x), 0x138, 0xf, 0xf, true));
}
template <int C>
__device__ __forceinline__ float dppmax(float m) {
    return fmaxf(m, __int_as_float(
        __builtin_amdgcn_update_dpp(0, __float_as_int(m), C, 0xf, 0xf, true)));
}

__global__ void __launch_bounds__(64, 1) ctc_fwd(const int* __restrict__ y_true,
                                                 const float* __restrict__ y_pred,
                                                 float* __restrict__ out) {
    __shared__ float lds[2 * LBUF];                     // 25.6 KB

    const int b = blockIdx.x;
    const int l = threadIdx.x;                          // lane 0..63
    const float* __restrict__ yp = y_pred + (size_t)b * (Tv * Cv);

    const int lab   = y_true[b * Lv + l];               // label l (< 95)
    const int labm1 = __shfl_up(lab, 1);
    const bool skip = (l > 0) && (lab != labm1);

    // per-lane LDS byte offsets for the 12 staged float4 slots
    // slot i: flat float4 f = i*64+l; row = f/24; col4 = f%24
#define WA(i) ((((i)*64 + l) / 24) * 400 + (((i)*64 + l) % 24) * 16)
    const int wa0 = WA(0),  wa1 = WA(1),  wa2 = WA(2),  wa3 = WA(3);
    const int wa4 = WA(4),  wa5 = WA(5),  wa6 = WA(6),  wa7 = WA(7);
    const int wa8 = WA(8),  wa9 = WA(9), wa10 = WA(10), wa11 = WA(11);
#undef WA

    // two independent staging sets -> prefetch distance of 2 chunks,
    // vmcnt tracked per register set (younger set stays in flight across
    // the older set's wait).
    float4 G0, G1, G2, G3, G4, G5, G6, G7, G8, G9, G10, G11;
    float4 H0, H1, H2, H3, H4, H5, H6, H7, H8, H9, H10, H11;
#define GLOADS(S, g) do { const float* gp_ = (g) + l * 4;                    \
    S##0 = *(const float4*)(gp_ +    0); S##1 = *(const float4*)(gp_ +  256);\
    S##2 = *(const float4*)(gp_ +  512); S##3 = *(const float4*)(gp_ +  768);\
    S##4 = *(const float4*)(gp_ + 1024); S##5 = *(const float4*)(gp_ + 1280);\
    S##6 = *(const float4*)(gp_ + 1536); S##7 = *(const float4*)(gp_ + 1792);\
    S##8 = *(const float4*)(gp_ + 2048); S##9 = *(const float4*)(gp_ + 2304);\
    S##10= *(const float4*)(gp_ + 2560); S##11= *(const float4*)(gp_ + 2816);} while (0)
    // EPS folded in at stage time: every consumer wants p + EPS, and this
    // moves the add off the per-step critical chain.
#define E4(v) make_float4((v).x + EPSf, (v).y + EPSf, (v).z + EPSf, (v).w + EPSf)
#define SWRITES(S, bufn) do { char* p_ = (char*)(bufn);                      \
    *(float4*)(p_ + wa0) = E4(S##0);  *(float4*)(p_ + wa1) = E4(S##1);       \
    *(float4*)(p_ + wa2) = E4(S##2);  *(float4*)(p_ + wa3) = E4(S##3);       \
    *(float4*)(p_ + wa4) = E4(S##4);  *(float4*)(p_ + wa5) = E4(S##5);       \
    *(float4*)(p_ + wa6) = E4(S##6);  *(float4*)(p_ + wa7) = E4(S##7);       \
    *(float4*)(p_ + wa8) = E4(S##8);  *(float4*)(p_ + wa9) = E4(S##9);       \
    *(float4*)(p_ + wa10)= E4(S##10); *(float4*)(p_ + wa11)= E4(S##11); } while (0)

    // double-buffered p-value sets (named scalars only; arrays are banned)
    float AB0,AB1,AB2,AB3,AB4,AB5,AB6,AB7, AL0,AL1,AL2,AL3,AL4,AL5,AL6,AL7;
    float BB0,BB1,BB2,BB3,BB4,BB5,BB6,BB7, BL0,BL1,BL2,BL3,BL4,BL5,BL6,BL7;
#define LOAD8(P, bb, r0) do { const float* pB_ = (bb) + BLANK;               \
    const float* pL_ = (bb) + lab;                                           \
    P##B0 = pB_[((r0)+0)*RS]; P##L0 = pL_[((r0)+0)*RS];                      \
    P##B1 = pB_[((r0)+1)*RS]; P##L1 = pL_[((r0)+1)*RS];                      \
    P##B2 = pB_[((r0)+2)*RS]; P##L2 = pL_[((r0)+2)*RS];                      \
    P##B3 = pB_[((r0)+3)*RS]; P##L3 = pL_[((r0)+3)*RS];                      \
    P##B4 = pB_[((r0)+4)*RS]; P##L4 = pL_[((r0)+4)*RS];                      \
    P##B5 = pB_[((r0)+5)*RS]; P##L5 = pL_[((r0)+5)*RS];                      \
    P##B6 = pB_[((r0)+6)*RS]; P##L6 = pL_[((r0)+6)*RS];                      \
    P##B7 = pB_[((r0)+7)*RS]; P##L7 = pL_[((r0)+7)*RS]; } while (0)

    float a0, a1, a2;                  // states 2l, 2l+1, 128(lane63)
    int   e_acc = 0;
    float sc_p = 1.0f; int e_p = 0;    // pending renorm (lag-applied)

    auto step = [&](float pb, float pl) {              // EPS already folded in
        float pls = skip ? pl : 0.0f;
        float a1p = dpp_shr1(a1);                      // alpha[2l-1]; lane0->0
        float t01 = a0 + a1;
        float na1 = fmaf(a1p, pls, t01 * pl);          // state 2l+1
        float na0 = fmaf(a1p, pb, a0 * pb);            // state 2l
        float na2 = (a2 + a1) * pb;                    // state 128 (lane63)
        a0 = na0; a1 = na1; a2 = na2;
    };
    auto rn_apply = [&]() {                            // apply 8-step-old scale
        a0 *= sc_p; a1 *= sc_p; a2 *= sc_p; e_acc += e_p;
    };
    auto rn_compute = [&]() {                          // off-chain wave max
        float m = fmaxf(fmaxf(a0, a1), a2);
        m = dppmax<0x111>(m); m = dppmax<0x112>(m); m = dppmax<0x114>(m);
        m = dppmax<0x118>(m); m = dppmax<0x142>(m); m = dppmax<0x143>(m);
        float mw = __int_as_float(__builtin_amdgcn_readlane(__float_as_int(m), 63));
        int e; (void)frexpf(mw, &e);                   // mw = f*2^e
        sc_p = ldexpf(1.0f, -e); e_p = e;              // exact pow2 scale
    };
#define GROUP8(P) do {                                                       \
    step(P##B0, P##L0); step(P##B1, P##L1); step(P##B2, P##L2);              \
    step(P##B3, P##L3); rn_apply();                                          \
    step(P##B4, P##L4); step(P##B5, P##L5); step(P##B6, P##L6);              \
    step(P##B7, P##L7); rn_compute(); } while (0)

    // ---- prologue: ch0 -> buf0 (via G); ch1 in flight in H; ch2 in flight
    //      in G; A <- rows 0-7 of ch0 ----
    GLOADS(G, yp);                     // ch0
    GLOADS(H, yp + CF);                // ch1 (issued before ch0's wait)
    SWRITES(G, lds);                   // waits only G's 12 loads (vmcnt(12))
    GLOADS(G, yp + 2 * CF);            // ch2
    LOAD8(A, lds, 0);
    const bool lane0 = (l == 0);
    a0 = lane0 ? AB0 : 0.0f;           // t=0 init (EPS already staged)
    a1 = lane0 ? AL0 : 0.0f;
    a2 = 0.0f;

    float* const buf0 = lds;
    float* const buf1 = lds + LBUF;

    // invariant at top of even chunk c: buf0 = ch c; H = ch c+1 (in flight);
    // G = ch c+2 (in flight).
    for (int c = 0; c < NCH; c += 2) {
        // ---------- even chunk c (data in buf0); write ch c+1 from H ------
        LOAD8(B, buf0, 8);                             // rows 8-15
        if (c == 0) {                                  // init + 7 steps (t=1..7)
            step(AB1, AL1); step(AB2, AL2); step(AB3, AL3); rn_apply();
            step(AB4, AL4); step(AB5, AL5); step(AB6, AL6); step(AB7, AL7);
            rn_compute();
        } else {
            GROUP8(A);                                 // rows 0-7
        }
        LOAD8(A, buf0, 16);                            // rows 16-23
        GROUP8(B);                                     // rows 8-15
        LOAD8(B, buf0, 24);                            // rows 24-31
        GROUP8(A);                                     // rows 16-23
        SWRITES(H, buf1);                              // ch c+1 (c<15 always)
        if (c + 3 < NCH) GLOADS(H, yp + (size_t)(c + 3) * CF);  // ch c+3
        LOAD8(A, buf1, 0);                             // next chunk rows 0-7
        GROUP8(B);                                     // rows 24-31

        // ---------- odd chunk c+1 (data in buf1); write ch c+2 from G -----
        LOAD8(B, buf1, 8);
        GROUP8(A);                                     // rows 0-7
        LOAD8(A, buf1, 16);
        GROUP8(B);                                     // rows 8-15
        LOAD8(B, buf1, 24);
        GROUP8(A);                                     // rows 16-23
        if (c + 1 < NCH - 1) SWRITES(G, buf0);         // ch c+2
        if (c + 4 < NCH) GLOADS(G, yp + (size_t)(c + 4) * CF);  // ch c+4
        if (c + 1 < NCH - 1) LOAD8(A, buf0, 0);        // next chunk rows 0-7
        GROUP8(B);                                     // rows 24-31
    }

    // ---- loss = -logaddexp(alpha[127], alpha[128]) (pending scale unapplied
    //      on purpose: e_acc counts exactly the applied scales) ----
    if (l == 63) {
        float sum = a1 + a2;
        out[b] = -(logf(sum) + (float)e_acc * 0.69314718055994530942f);
    }
#undef GLOADS
#undef SWRITES
#undef E4
#undef LOAD8
#undef GROUP8
}

extern "C" void kernel_launch(void* const* d_in, const int* in_sizes, int n_in,
                              void* d_out, int out_size, void* d_ws, size_t ws_size,
                              hipStream_t stream) {
    const int*   y_true = (const int*)d_in[0];   // [512, 64] int32
    const float* y_pred = (const float*)d_in[1]; // [512, 512, 96] fp32
    float*       out    = (float*)d_out;         // [512, 1] fp32
    (void)in_sizes; (void)n_in; (void)out_size; (void)d_ws; (void)ws_size;
    ctc_fwd<<<Bv, 64, 0, stream>>>(y_true, y_pred, out);
}

// Round 2
// 149.776 us; speedup vs baseline: 1.0003x; 1.0003x over previous
//
#include <hip/hip_runtime.h>
#include <math.h>

// CTC batch cost (keras.backend.ctc_batch_cost, full lengths).
// B=512, T=512, C=96 (blank=95), L=64, S=2L+1=129.
//
// Round 7: producer/consumer wave split.
//  - R6 post-mortem: deeper register prefetch was NEUTRAL -> the single
//    wave's serialized issue stream (64 ds_read + ~300 VALU + staging per
//    chunk, 1 wave/SIMD, zero TLP) is the bottleneck, not vmcnt placement.
//  - Now: 128 threads/block = 2 waves. Wave 0 (consumer) runs the
//    recurrence only: ds_read_b32 + VALU, ~1k cyc/chunk. Wave 1 (producer)
//    does ALL global->reg->LDS staging. Waves sit on different SIMDs, so
//    staging issue + HBM latency overlap compute fully.
//  - Sync: plain __syncthreads() at workgroup-uniform points, once per
//    chunk. The vmcnt(0) drain it implies lands on the PRODUCER wave and
//    is hidden under consumer compute. No raw-barrier/counted-vmcnt races.
//  - Producer keeps G/H register sets so ds_writes never wait on vmcnt
//    (loads for chunk c+3/c+4 are issued one body ahead and drained by the
//    intervening barrier).
//  - EPS folded into staged values (producer-side VALU, off the chain).

constexpr int Bv = 512;
constexpr int Tv = 512;
constexpr int Cv = 96;
constexpr int Lv = 64;
constexpr int BLANK = Cv - 1;        // 95
constexpr float EPSf = 1e-7f;

constexpr int ROWS = 32;             // rows per chunk
constexpr int NCH  = Tv / ROWS;      // 16 chunks
constexpr int CF   = ROWS * Cv;      // 3072 floats per chunk in global
constexpr int RS   = 100;            // padded LDS row stride (floats); 400 B
constexpr int LBUF = ROWS * RS;      // 3200 floats per LDS buffer

__device__ __forceinline__ float dpp_shr1(float x) {   // lane i <- i-1; lane0 <- 0
    return __int_as_float(
        __builtin_amdgcn_update_dpp(0, __float_as_int(x), 0x138, 0xf, 0xf, true));
}
template <int C>
__device__ __forceinline__ float dppmax(float m) {
    return fmaxf(m, __int_as_float(
        __builtin_amdgcn_update_dpp(0, __float_as_int(m), C, 0xf, 0xf, true)));
}

__global__ void __launch_bounds__(128, 1) ctc_fwd(const int* __restrict__ y_true,
                                                  const float* __restrict__ y_pred,
                                                  float* __restrict__ out) {
    __shared__ float lds[2 * LBUF];                     // 25.6 KB

    const int b   = blockIdx.x;
    const int tid = threadIdx.x;
    const int wid = tid >> 6;                           // 0 = consumer, 1 = producer
    const int l   = tid & 63;                           // lane within wave
    const float* __restrict__ yp = y_pred + (size_t)b * (Tv * Cv);

    const int lab   = y_true[b * Lv + l];               // label l (< 95)
    const int labm1 = __shfl_up(lab, 1);
    const bool skip = (l > 0) && (lab != labm1);

    // per-lane LDS byte offsets for the 12 staged float4 slots (producer)
    // slot i: flat float4 f = i*64+l; row = f/24; col4 = f%24
#define WA(i) ((((i)*64 + l) / 24) * 400 + (((i)*64 + l) % 24) * 16)
    const int wa0 = WA(0),  wa1 = WA(1),  wa2 = WA(2),  wa3 = WA(3);
    const int wa4 = WA(4),  wa5 = WA(5),  wa6 = WA(6),  wa7 = WA(7);
    const int wa8 = WA(8),  wa9 = WA(9), wa10 = WA(10), wa11 = WA(11);
#undef WA

    // two producer staging sets: loads for chunk c+3/c+4 issued one body
    // ahead; the intervening __syncthreads drains them, so SWRITES never
    // waits on vmcnt.
    float4 G0, G1, G2, G3, G4, G5, G6, G7, G8, G9, G10, G11;
    float4 H0, H1, H2, H3, H4, H5, H6, H7, H8, H9, H10, H11;
#define GLOADS(S, g) do { const float* gp_ = (g) + l * 4;                    \
    S##0 = *(const float4*)(gp_ +    0); S##1 = *(const float4*)(gp_ +  256);\
    S##2 = *(const float4*)(gp_ +  512); S##3 = *(const float4*)(gp_ +  768);\
    S##4 = *(const float4*)(gp_ + 1024); S##5 = *(const float4*)(gp_ + 1280);\
    S##6 = *(const float4*)(gp_ + 1536); S##7 = *(const float4*)(gp_ + 1792);\
    S##8 = *(const float4*)(gp_ + 2048); S##9 = *(const float4*)(gp_ + 2304);\
    S##10= *(const float4*)(gp_ + 2560); S##11= *(const float4*)(gp_ + 2816);} while (0)
#define E4(v) make_float4((v).x + EPSf, (v).y + EPSf, (v).z + EPSf, (v).w + EPSf)
#define SWRITES(S, bufn) do { char* p_ = (char*)(bufn);                      \
    *(float4*)(p_ + wa0) = E4(S##0);  *(float4*)(p_ + wa1) = E4(S##1);       \
    *(float4*)(p_ + wa2) = E4(S##2);  *(float4*)(p_ + wa3) = E4(S##3);       \
    *(float4*)(p_ + wa4) = E4(S##4);  *(float4*)(p_ + wa5) = E4(S##5);       \
    *(float4*)(p_ + wa6) = E4(S##6);  *(float4*)(p_ + wa7) = E4(S##7);       \
    *(float4*)(p_ + wa8) = E4(S##8);  *(float4*)(p_ + wa9) = E4(S##9);       \
    *(float4*)(p_ + wa10)= E4(S##10); *(float4*)(p_ + wa11)= E4(S##11); } while (0)

    // consumer double-buffered p-value sets (named scalars only)
    float AB0,AB1,AB2,AB3,AB4,AB5,AB6,AB7, AL0,AL1,AL2,AL3,AL4,AL5,AL6,AL7;
    float BB0,BB1,BB2,BB3,BB4,BB5,BB6,BB7, BL0,BL1,BL2,BL3,BL4,BL5,BL6,BL7;
#define LOAD8(P, bb, r0) do { const float* pB_ = (bb) + BLANK;               \
    const float* pL_ = (bb) + lab;                                           \
    P##B0 = pB_[((r0)+0)*RS]; P##L0 = pL_[((r0)+0)*RS];                      \
    P##B1 = pB_[((r0)+1)*RS]; P##L1 = pL_[((r0)+1)*RS];                      \
    P##B2 = pB_[((r0)+2)*RS]; P##L2 = pL_[((r0)+2)*RS];                      \
    P##B3 = pB_[((r0)+3)*RS]; P##L3 = pL_[((r0)+3)*RS];                      \
    P##B4 = pB_[((r0)+4)*RS]; P##L4 = pL_[((r0)+4)*RS];                      \
    P##B5 = pB_[((r0)+5)*RS]; P##L5 = pL_[((r0)+5)*RS];                      \
    P##B6 = pB_[((r0)+6)*RS]; P##L6 = pL_[((r0)+6)*RS];                      \
    P##B7 = pB_[((r0)+7)*RS]; P##L7 = pL_[((r0)+7)*RS]; } while (0)

    float a0, a1, a2;                  // states 2l, 2l+1, 128(lane63)
    int   e_acc = 0;
    float sc_p = 1.0f; int e_p = 0;    // pending renorm (lag-applied)
    const bool lane0 = (l == 0);

    auto step = [&](float pb, float pl) {              // EPS already folded in
        float pls = skip ? pl : 0.0f;
        float a1p = dpp_shr1(a1);                      // alpha[2l-1]; lane0->0
        float t01 = a0 + a1;
        float na1 = fmaf(a1p, pls, t01 * pl);          // state 2l+1
        float na0 = fmaf(a1p, pb, a0 * pb);            // state 2l
        float na2 = (a2 + a1) * pb;                    // state 128 (lane63)
        a0 = na0; a1 = na1; a2 = na2;
    };
    auto rn_apply = [&]() {                            // apply 8-step-old scale
        a0 *= sc_p; a1 *= sc_p; a2 *= sc_p; e_acc += e_p;
    };
    auto rn_compute = [&]() {                          // off-chain wave max
        float m = fmaxf(fmaxf(a0, a1), a2);
        m = dppmax<0x111>(m); m = dppmax<0x112>(m); m = dppmax<0x114>(m);
        m = dppmax<0x118>(m); m = dppmax<0x142>(m); m = dppmax<0x143>(m);
        float mw = __int_as_float(__builtin_amdgcn_readlane(__float_as_int(m), 63));
        int e; (void)frexpf(mw, &e);                   // mw = f*2^e
        sc_p = ldexpf(1.0f, -e); e_p = e;              // exact pow2 scale
    };
#define GROUP8(P) do {                                                       \
    step(P##B0, P##L0); step(P##B1, P##L1); step(P##B2, P##L2);              \
    step(P##B3, P##L3); rn_apply();                                          \
    step(P##B4, P##L4); step(P##B5, P##L5); step(P##B6, P##L6);              \
    step(P##B7, P##L7); rn_compute(); } while (0)

    // consume one 32-row chunk from LDS buffer bb; FIRST handles t=0 init
#define CONSUME(bb, FIRST) do {                                              \
    LOAD8(A, (bb), 0);                                                       \
    LOAD8(B, (bb), 8);                                                       \
    if (FIRST) {                                                             \
        a0 = lane0 ? AB0 : 0.0f;   /* t=0 init (EPS already staged) */       \
        a1 = lane0 ? AL0 : 0.0f;                                             \
        a2 = 0.0f;                                                           \
        step(AB1, AL1); step(AB2, AL2); step(AB3, AL3); rn_apply();          \
        step(AB4, AL4); step(AB5, AL5); step(AB6, AL6); step(AB7, AL7);      \
        rn_compute();                                                        \
    } else {                                                                 \
        GROUP8(A);                                                           \
    }                                                                        \
    LOAD8(A, (bb), 16);                                                      \
    GROUP8(B);                                                               \
    LOAD8(B, (bb), 24);                                                      \
    GROUP8(A);                                                               \
    GROUP8(B);                                                               \
} while (0)

    float* const buf0 = lds;
    float* const buf1 = lds + LBUF;

    // ---- prologue (producer): ch0 -> buf0; ch1 in H, ch2 in G in flight;
    //      the barrier's vmcnt(0) drain completes them. ----
    if (wid) {
        GLOADS(G, yp);                 // ch0
        GLOADS(H, yp + CF);            // ch1
        SWRITES(G, lds);               // waits only G's 12 loads
        GLOADS(G, yp + 2 * CF);        // ch2
    }
    __syncthreads();                   // buf0 = ch0 ready; H,G complete

    // invariant at top of body c (even): buf0 = ch c; H = ch c+1 (complete);
    // G = ch c+2 (complete).
    for (int c = 0; c < NCH; c += 2) {
        if (wid) {
            SWRITES(H, buf1);                          // ch c+1 (no vmcnt wait)
            if (c + 3 < NCH) GLOADS(H, yp + (size_t)(c + 3) * CF);
        } else {
            CONSUME(buf0, c == 0);                     // chunk c
        }
        __syncthreads();               // buf1 = ch c+1; buf0 free; H drained
        if (wid) {
            if (c + 2 < NCH) SWRITES(G, buf0);         // ch c+2
            if (c + 4 < NCH) GLOADS(G, yp + (size_t)(c + 4) * CF);
        } else {
            CONSUME(buf1, false);                      // chunk c+1
        }
        __syncthreads();               // buf0 = ch c+2; buf1 free; G drained
    }

    // ---- loss = -logaddexp(alpha[127], alpha[128]) (pending scale unapplied
    //      on purpose: e_acc counts exactly the applied scales) ----
    if (tid == 63) {                   // consumer wave, lane 63
        float sum = a1 + a2;
        out[b] = -(logf(sum) + (float)e_acc * 0.69314718055994530942f);
    }
#undef GLOADS
#undef SWRITES
#undef E4
#undef LOAD8
#undef GROUP8
#undef CONSUME
}

extern "C" void kernel_launch(void* const* d_in, const int* in_sizes, int n_in,
                              void* d_out, int out_size, void* d_ws, size_t ws_size,
                              hipStream_t stream) {
    const int*   y_true = (const int*)d_in[0];   // [512, 64] int32
    const float* y_pred = (const float*)d_in[1]; // [512, 512, 96] fp32
    float*       out    = (float*)d_out;         // [512, 1] fp32
    (void)in_sizes; (void)n_in; (void)out_size; (void)d_ws; (void)ws_size;
    ctc_fwd<<<Bv, 128, 0, stream>>>(y_true, y_pred, out);
}